// Round 11
// baseline (741.531 us; speedup 1.0000x reference)
//
#include <hip/hip_runtime.h>
#include <math.h>

#define NB 512
#define DD 32
#define NPX 1024      // 32*32
#define NTOT 524288   // 512*1024
#define NC 512
#define CD 64

typedef float v2f __attribute__((ext_vector_type(2)));
typedef _Float16 hf;
typedef hf hf8 __attribute__((ext_vector_type(8)));
typedef float f32x4 __attribute__((ext_vector_type(4)));

__device__ __forceinline__ v2f pkfma(v2f a, v2f b, v2f c) {
    return __builtin_elementwise_fma(a, b, c);
}
__device__ __forceinline__ v2f splat2(float s) { v2f r; r.x = s; r.y = s; return r; }

__device__ __forceinline__ f32x4 mfma16(hf8 a, hf8 b, f32x4 c) {
    return __builtin_amdgcn_mfma_f32_16x16x32_f16(a, b, c, 0, 0, 0);
}

// numpy pairwise-8 sum of squares over 64 contiguous elements.
__device__ __forceinline__ float np_sumsq64(const float* a, int stride) {
    float r[8];
    #pragma unroll
    for (int j = 0; j < 8; ++j) {
        float v = a[j * stride];
        r[j] = __fmul_rn(v, v);
    }
    #pragma unroll
    for (int i = 1; i < 8; ++i)
        #pragma unroll
        for (int j = 0; j < 8; ++j) {
            float v = a[(i * 8 + j) * stride];
            r[j] = __fadd_rn(r[j], __fmul_rn(v, v));
        }
    return __fadd_rn(__fadd_rn(__fadd_rn(r[0], r[1]), __fadd_rn(r[2], r[3])),
                     __fadd_rn(__fadd_rn(r[4], r[5]), __fadd_rn(r[6], r[7])));
}

// ---------------- conv1 (+ folded init: cnorm, cb-split, w2-split-transpose) ----------------
__global__ __launch_bounds__(256) void k_conv1(const float* __restrict__ x,
                                               const float* __restrict__ w,
                                               const float* __restrict__ bias,
                                               float* __restrict__ h1,
                                               const float* __restrict__ cb,
                                               const float* __restrict__ c2w,
                                               float* __restrict__ cnorm,
                                               hf* __restrict__ cbh,
                                               hf* __restrict__ cbl,
                                               hf* __restrict__ wTh,
                                               hf* __restrict__ wTl,
                                               float* __restrict__ accv) {
    const int b = blockIdx.x;
    const int tid = threadIdx.x;
    {   // folded side work on low blocks (independent of conv)
        int t = b * 256 + tid;
        if (t < NC)
            cnorm[t] = np_sumsq64(cb + (size_t)t * CD, 1);
        if (b < 128) {   // t < 32768: split codebook into scaled f16 hi/lo
            float a = cb[t] * 256.f;             // exact pow2 scale
            hf h0 = (hf)a;
            float rl = (a - (float)h0) * 2048.f; // exact (Sterbenz + pow2)
            cbh[t] = h0;
            cbl[t] = (hf)rl;
        }
        if (b >= 128 && b < 200) {   // split+transpose conv2 weights: wT[s9][co][ci]
            int t2 = (b - 128) * 256 + tid;
            if (t2 < 18432) {
                int s9 = t2 >> 11, rem = t2 & 2047;
                int co = rem >> 5, ci = rem & 31;
                float a = c2w[s9 * 2048 + ci * 64 + co] * 256.f;
                hf h0 = (hf)a;
                float rl = (a - (float)h0) * 2048.f;
                wTh[t2] = h0;    // t2 = (s9*64+co)*32 + ci
                wTl[t2] = (hf)rl;
            }
        }
        if (t == 0) accv[0] = 0.f;
    }
    __shared__ float xs[34][34];
    for (int i = tid; i < 34 * 34; i += 256) {
        int yy = i / 34, xx = i - yy * 34;
        float v = 0.f;
        if (yy >= 1 && yy <= 32 && xx >= 1 && xx <= 32)
            v = x[(size_t)b * NPX + (yy - 1) * 32 + (xx - 1)];
        xs[yy][xx] = v;
    }
    __syncthreads();
    for (int rep = 0; rep < 4; ++rep) {
        int px = tid + rep * 256;
        int y = px >> 5, xc = px & 31;
        v2f acc2[16];
        #pragma unroll
        for (int c = 0; c < 16; ++c) acc2[c] = splat2(0.f);
        #pragma unroll
        for (int dy = 0; dy < 3; ++dy)
        #pragma unroll
        for (int dx = 0; dx < 3; ++dx) {
            float a = xs[y + dy][xc + dx];
            v2f av = splat2(a);
            const v2f* wr = (const v2f*)(w + (dy * 3 + dx) * 32);
            #pragma unroll
            for (int c = 0; c < 16; ++c) acc2[c] = pkfma(av, wr[c], acc2[c]);
        }
        float4* out = (float4*)(h1 + ((size_t)b * NPX + px) * 32);
        #pragma unroll
        for (int q = 0; q < 8; ++q) {
            float4 v;
            v.x = fmaxf(__fadd_rn(acc2[q*2+0].x, bias[q*4+0]), 0.f);
            v.y = fmaxf(__fadd_rn(acc2[q*2+0].y, bias[q*4+1]), 0.f);
            v.z = fmaxf(__fadd_rn(acc2[q*2+1].x, bias[q*4+2]), 0.f);
            v.w = fmaxf(__fadd_rn(acc2[q*2+1].y, bias[q*4+3]), 0.f);
            out[q] = v;
        }
    }
}

// ---------------- conv2 via 4-term split-f16 MFMA (R9 passing version) ----------------
#define CI_P 40
__global__ __launch_bounds__(512, 4) void k_conv2(const float* __restrict__ h1,
                                                  const hf* __restrict__ wTh,
                                                  const hf* __restrict__ wTl,
                                                  const float* __restrict__ bias,
                                                  float* __restrict__ h) {
    __shared__ hf Ah[10 * 34 * CI_P];   // 27.2 KB
    __shared__ hf Al[10 * 34 * CI_P];   // 27.2 KB
    const int blk = blockIdx.x;
    const int b = blk >> 2, strip = blk & 3;
    const int r0 = strip * 8;
    const int tid = threadIdx.x;
    for (int i = tid; i < 640; i += 512) {   // zero-pad x columns 0 and 33
        int ci = i & 31, rem = i >> 5;       // rem 0..19
        int ry = rem >> 1, colx = (rem & 1) * 33;
        int idx = (ry * 34 + colx) * CI_P + ci;
        Ah[idx] = (hf)0.f;
        Al[idx] = (hf)0.f;
    }
    #pragma unroll
    for (int r = 0; r < 5; ++r) {        // 2560 float4 = 10 rows x 32x x 8ci4
        int j = tid + r * 512;
        int ci4 = j & 7, xc = (j >> 3) & 31, ry = j >> 8;   // ry 0..9
        int gy = r0 - 1 + ry;
        float4 v = make_float4(0.f, 0.f, 0.f, 0.f);
        if (gy >= 0 && gy < 32)
            v = *(const float4*)(h1 + ((size_t)b * NPX + gy * 32 + xc) * 32 + ci4 * 4);
        int bi = (ry * 34 + xc + 1) * CI_P + ci4 * 4;
        float fv[4] = {v.x, v.y, v.z, v.w};
        #pragma unroll
        for (int q = 0; q < 4; ++q) {
            float a = fv[q] * 256.f;               // exact pow2 scale
            hf h0 = (hf)a;
            float rl = (a - (float)h0) * 2048.f;   // exact
            Ah[bi + q] = h0;
            Al[bi + q] = (hf)rl;
        }
    }
    __syncthreads();
    const int w = tid >> 6, l = tid & 63;   // wave w owns strip-row w (32 px)
    const int i16 = l & 15, j4 = l >> 4;
    #pragma unroll 1
    for (int ntp = 0; ntp < 2; ++ntp) {     // N-tile pairs: co [0,32), [32,64)
        f32x4 hi[2][2], mid[2][2], llt[2][2];   // [m-subtile][ntl]
        #pragma unroll
        for (int s = 0; s < 2; ++s)
            #pragma unroll
            for (int n = 0; n < 2; ++n) {
                hi[s][n] = f32x4{0.f, 0.f, 0.f, 0.f};
                mid[s][n] = f32x4{0.f, 0.f, 0.f, 0.f};
                llt[s][n] = f32x4{0.f, 0.f, 0.f, 0.f};
            }
        #pragma unroll 1
        for (int s9 = 0; s9 < 9; ++s9) {
            const int dy = s9 / 3, dx = s9 - dy * 3;
            hf8 a_h[2], a_l[2];
            #pragma unroll
            for (int s = 0; s < 2; ++s) {
                int ofs = ((w + dy) * 34 + (s * 16 + i16 + dx)) * CI_P + 8 * j4;
                a_h[s] = *(const hf8*)(Ah + ofs);
                a_l[s] = *(const hf8*)(Al + ofs);
            }
            #pragma unroll
            for (int ntl = 0; ntl < 2; ++ntl) {
                const int nt = ntp * 2 + ntl;
                const int wofs = (s9 * 64 + nt * 16 + i16) * 32 + 8 * j4;
                const hf8 b_h = *(const hf8*)(wTh + wofs);
                const hf8 b_l = *(const hf8*)(wTl + wofs);
                #pragma unroll
                for (int s = 0; s < 2; ++s) {
                    hi[s][ntl]  = mfma16(a_h[s], b_h, hi[s][ntl]);
                    mid[s][ntl] = mfma16(a_h[s], b_l, mid[s][ntl]);
                    mid[s][ntl] = mfma16(a_l[s], b_h, mid[s][ntl]);
                    llt[s][ntl] = mfma16(a_l[s], b_l, llt[s][ntl]);
                }
            }
        }
        #pragma unroll
        for (int ntl = 0; ntl < 2; ++ntl) {
            const int co = (ntp * 2 + ntl) * 16 + i16;
            const float bco = bias[co];
            #pragma unroll
            for (int s = 0; s < 2; ++s) {
                #pragma unroll
                for (int r = 0; r < 4; ++r) {
                    float comb = fmaf(mid[s][ntl][r], 4.8828125e-4f,
                                 fmaf(llt[s][ntl][r], 2.384185791015625e-7f,
                                      hi[s][ntl][r]));
                    float hv = fmaxf(
                        __fadd_rn(__fmul_rn(comb, 1.52587890625e-5f), bco), 0.f);
                    int px = w * 32 + s * 16 + j4 * 4 + r;
                    h[((size_t)b * NPX + r0 * 32 + px) * 64 + co] = hv;
                }
            }
        }
    }
}

// ---------------- VQ: 2-term split-f16 MFMA screener + certified exact rescue ----------------
// Screener tracks d' = cn - (2/65536)*dot (per-pixel constant H dropped: argmin and the
// top-2 gap are invariant to it). 2-term split error B ~1e-4 << TAU/2; gap > TAU certifies
// the approx winner = exact fp32 winner. Gap <= TAU -> block recomputes that pixel's h
// EXACTLY (R12 chain from h1) -> exact H -> exact 512 distances -> numpy first-occurrence.
// B-operand loads ping-pong one tile ahead (registers) to hide L1/L2 latency; VGPR budget
// 128 at (512,4) -- R6's spill failure was the 64-VGPR (256,4) budget, not the structure.
#define TAU 1e-3f
__global__ __launch_bounds__(512, 4) void k_vq(const float* __restrict__ h,
                                               const float* __restrict__ h1,
                                               const float* __restrict__ c2w,
                                               const float* __restrict__ c2b,
                                               const float* __restrict__ cb,
                                               const hf* __restrict__ cbh,
                                               const hf* __restrict__ cbl,
                                               const float* __restrict__ cnorm,
                                               int* __restrict__ idxout,
                                               float* __restrict__ fidx,
                                               float* __restrict__ lossacc) {
    __shared__ float4 Ats[16][256];   // 64 KB
    __shared__ float cn_lds[512];
    __shared__ int   mis_lds[256];
    __shared__ float r_v[512];
    __shared__ int   r_i[512];
    __shared__ int   rlist[256];
    __shared__ float hex_lds[64];
    __shared__ int   rcnt;
    const int tid = threadIdx.x;
    const size_t base = (size_t)blockIdx.x * 256;
    if (tid == 0) rcnt = 0;
    {   // stage h rows
        const int px = tid & 255, half = tid >> 8;
        const float4* src = (const float4*)(h + (base + px) * 64 + half * 32);
        #pragma unroll
        for (int j = 0; j < 8; ++j)
            Ats[half * 8 + j][px] = src[j];
    }
    cn_lds[tid] = cnorm[tid];
    __syncthreads();
    const int w = tid >> 6, l = tid & 63;
    const int co = l & 15, g = l >> 4;
    const int pxw = w * 32;
    hf8 ah[2][2], al[2][2];
    #pragma unroll
    for (int s = 0; s < 2; ++s)
        #pragma unroll
        for (int ks = 0; ks < 2; ++ks) {
            float4 q0 = Ats[ks * 8 + g * 2 + 0][pxw + s * 16 + co];
            float4 q1 = Ats[ks * 8 + g * 2 + 1][pxw + s * 16 + co];
            float fv[8] = {q0.x, q0.y, q0.z, q0.w, q1.x, q1.y, q1.z, q1.w};
            #pragma unroll
            for (int j = 0; j < 8; ++j) {
                float fa = fv[j] * 256.f;
                hf h0 = (hf)fa;
                float rl = (fa - (float)h0) * 2048.f;
                ah[s][ks][j] = h0;
                al[s][ks][j] = (hf)rl;
            }
        }
    float minv[2][4], min2[2][4];
    int   mini[2][4];
    #pragma unroll
    for (int s = 0; s < 2; ++s)
        #pragma unroll
        for (int r = 0; r < 4; ++r) {
            minv[s][r] = 3.4e38f; min2[s][r] = 3.4e38f; mini[s][r] = 0;
        }
    const hf* pbh = cbh + (size_t)co * 64 + g * 8;
    const hf* pbl = cbl + (size_t)co * 64 + g * 8;
    // ping-pong: current tile in Ch*/Cl*, next tile prefetched each iteration
    hf8 Ch0 = *(const hf8*)(pbh);
    hf8 Ch1 = *(const hf8*)(pbh + 32);
    hf8 Cl0 = *(const hf8*)(pbl);
    hf8 Cl1 = *(const hf8*)(pbl + 32);
    #pragma unroll 1
    for (int t = 0; t < 32; ++t) {
        const int tn = (t + 1 < 32) ? t + 1 : 31;   // clamped prefetch (branchless)
        hf8 Nh0 = *(const hf8*)(pbh + (size_t)tn * 1024);
        hf8 Nh1 = *(const hf8*)(pbh + (size_t)tn * 1024 + 32);
        hf8 Nl0 = *(const hf8*)(pbl + (size_t)tn * 1024);
        hf8 Nl1 = *(const hf8*)(pbl + (size_t)tn * 1024 + 32);
        const float cn = cn_lds[t * 16 + co];
        #pragma unroll
        for (int s = 0; s < 2; ++s) {
            f32x4 hi = {0.f, 0.f, 0.f, 0.f};
            f32x4 lo = {0.f, 0.f, 0.f, 0.f};
            lo = mfma16(ah[s][0], Cl0, lo);
            lo = mfma16(al[s][0], Ch0, lo);
            hi = mfma16(ah[s][0], Ch0, hi);
            lo = mfma16(ah[s][1], Cl1, lo);
            lo = mfma16(al[s][1], Ch1, lo);
            hi = mfma16(ah[s][1], Ch1, hi);
            #pragma unroll
            for (int r = 0; r < 4; ++r) {
                float comb = fmaf(lo[r], 4.8828125e-4f, hi[r]);
                float d = __fsub_rn(cn, __fmul_rn(3.0517578125e-5f, comb));
                if (d < minv[s][r]) {
                    min2[s][r] = minv[s][r];
                    minv[s][r] = d; mini[s][r] = t * 16 + co;
                } else if (d < min2[s][r]) {
                    min2[s][r] = d;
                }
            }
        }
        Ch0 = Nh0; Ch1 = Nh1; Cl0 = Nl0; Cl1 = Nl1;
    }
    #pragma unroll
    for (int s = 0; s < 2; ++s)
        #pragma unroll
        for (int r = 0; r < 4; ++r) {
            float v1 = minv[s][r], v2 = min2[s][r];
            int i1 = mini[s][r];
            #pragma unroll
            for (int off = 1; off < 16; off <<= 1) {
                float vo  = __shfl_xor(v1, off, 64);
                int   io  = __shfl_xor(i1, off, 64);
                float v2o = __shfl_xor(v2, off, 64);
                if (vo < v1 || (vo == v1 && io < i1)) {
                    v2 = fminf(v1, v2o);
                    v1 = vo; i1 = io;
                } else {
                    v2 = fminf(v2, vo);
                }
            }
            if (co == 0) {
                int pxo = pxw + s * 16 + g * 4 + r;
                mis_lds[pxo] = i1;
                if (v2 - v1 <= TAU) {
                    int slot = atomicAdd(&rcnt, 1);
                    rlist[slot] = pxo;
                }
            }
        }
    __syncthreads();
    // ---- certified exact rescue: exact h (R12 chain from h1) -> exact distances ----
    const int nresc = rcnt;
    for (int rr = 0; rr < nresc; ++rr) {
        const int px = rlist[rr];
        const int gpx = (int)base + px;
        const int bimg = gpx >> 10, pp = gpx & 1023;
        const int py = pp >> 5, pxx = pp & 31;
        if (tid < 64) {   // co = tid: exact conv2 chain (s9 asc, ci asc)
            float acc = 0.f;
            #pragma unroll 1
            for (int s9 = 0; s9 < 9; ++s9) {
                const int dy = s9 / 3, dx = s9 - dy * 3;
                const int gy = py + dy - 1, gx = pxx + dx - 1;
                if (gy >= 0 && gy < 32 && gx >= 0 && gx < 32) {
                    const float* hp = h1 + ((size_t)bimg * NPX + gy * 32 + gx) * 32;
                    const float* wp = c2w + s9 * 2048 + tid;
                    #pragma unroll
                    for (int ci = 0; ci < 32; ++ci)
                        acc = fmaf(hp[ci], wp[ci * 64], acc);
                }
            }
            hex_lds[tid] = fmaxf(__fadd_rn(acc, c2b[tid]), 0.f);
        }
        __syncthreads();
        const float Hp = np_sumsq64(hex_lds, 1);   // exact H (broadcast LDS reads)
        float acc0 = 0.f;
        const float* crow0 = cb + (size_t)tid * 64;
        #pragma unroll
        for (int kg = 0; kg < 16; ++kg) {
            acc0 = fmaf(hex_lds[kg*4+0], crow0[kg*4+0], acc0);
            acc0 = fmaf(hex_lds[kg*4+1], crow0[kg*4+1], acc0);
            acc0 = fmaf(hex_lds[kg*4+2], crow0[kg*4+2], acc0);
            acc0 = fmaf(hex_lds[kg*4+3], crow0[kg*4+3], acc0);
        }
        r_v[tid] = __fadd_rn(__fsub_rn(Hp, __fmul_rn(2.f, acc0)), cn_lds[tid]);
        r_i[tid] = tid;
        __syncthreads();
        for (int st = 256; st > 0; st >>= 1) {
            if (tid < st) {
                float vo = r_v[tid + st]; int io = r_i[tid + st];
                if (vo < r_v[tid] || (vo == r_v[tid] && io < r_i[tid])) {
                    r_v[tid] = vo; r_i[tid] = io;
                }
            }
            __syncthreads();
        }
        if (tid == 0) mis_lds[px] = r_i[0];
        __syncthreads();
    }
    // ---- outputs + loss epilogue ----
    if (tid < 256) {
        int bi = mis_lds[tid];
        idxout[base + tid] = bi;
        fidx[base + tid] = (float)bi;
        float ls = 0.f;
        const float* crow = cb + (size_t)bi * 64;
        #pragma unroll
        for (int kg = 0; kg < 16; ++kg) {
            float4 a = Ats[kg][tid];
            float d0 = crow[kg*4+0] - a.x;
            float d1 = crow[kg*4+1] - a.y;
            float d2 = crow[kg*4+2] - a.z;
            float d3 = crow[kg*4+3] - a.w;
            ls = fmaf(d0, d0, ls); ls = fmaf(d1, d1, ls);
            ls = fmaf(d2, d2, ls); ls = fmaf(d3, d3, ls);
        }
        #pragma unroll
        for (int off = 32; off > 0; off >>= 1)
            ls += __shfl_down(ls, off, 64);
        if ((tid & 63) == 0) atomicAdd(lossacc, ls);
    }
}

// ---------------- prep w1: split + transpose into blocked [k8][128 n][8 k] hf ----------------
__global__ __launch_bounds__(256) void k_prepw1(const float* __restrict__ w1,
                                                hf* __restrict__ w1h,
                                                hf* __restrict__ w1l) {
    int t = blockIdx.x * 256 + threadIdx.x;  // 0..1048575
    int n = t & 127, k8 = t >> 7;            // k8 0..8191
    hf vh[8], vl[8];
    #pragma unroll
    for (int j = 0; j < 8; ++j) {
        float a = w1[(size_t)(k8 * 8 + j) * 128 + n] * 256.f;  // exact pow2 scale
        hf h0 = (hf)a;
        float rl = (a - (float)h0) * 2048.f;                   // exact
        vh[j] = h0;
        vl[j] = (hf)rl;
    }
    *(hf8*)(w1h + (size_t)k8 * 1024 + n * 8) = *(hf8*)vh;
    *(hf8*)(w1l + (size_t)k8 * 1024 + n * 8) = *(hf8*)vl;
}

// ---------------- fc1 via 3-term split-f16 MFMA: emb @ w1 -> K-split partials ----------------
__global__ __launch_bounds__(256) void k_fc1(const int* __restrict__ idxw,
                                             const hf* __restrict__ cbh,
                                             const hf* __restrict__ cbl,
                                             const hf* __restrict__ w1h,
                                             const hf* __restrict__ w1l,
                                             float* __restrict__ part) {
    const int kchunk = blockIdx.x;       // 0..63  (16 pixels = K 1024)
    const int mtile  = blockIdx.y;       // 0..7   (64 images)
    const int tid = threadIdx.x;
    const int w = tid >> 6, l = tid & 63;    // wave = 16-img subtile
    const int co = l & 15, g = l >> 4;
    const int mbase = mtile * 64 + w * 16;
    f32x4 hi[8], mid[8];
    #pragma unroll
    for (int n = 0; n < 8; ++n) {
        hi[n] = f32x4{0.f, 0.f, 0.f, 0.f};
        mid[n] = f32x4{0.f, 0.f, 0.f, 0.f};
    }
    int code = 0;
    #pragma unroll 1
    for (int kstep = 0; kstep < 32; ++kstep) {   // 32 x K=32
        if ((kstep & 1) == 0) {
            const int pix = kchunk * 16 + (kstep >> 1);
            code = idxw[(size_t)(mbase + co) * NPX + pix];
        }
        const int koff = (kstep & 1) * 32 + g * 8;
        const hf8 ah = *(const hf8*)(cbh + ((size_t)code << 6) + koff);
        const hf8 al = *(const hf8*)(cbl + ((size_t)code << 6) + koff);
        const size_t k8b = (size_t)(kchunk * 128 + kstep * 4 + g) * 1024;
        #pragma unroll
        for (int n = 0; n < 8; ++n) {
            const hf8 bh = *(const hf8*)(w1h + k8b + (n * 16 + co) * 8);
            const hf8 bl = *(const hf8*)(w1l + k8b + (n * 16 + co) * 8);
            hi[n]  = mfma16(ah, bh, hi[n]);
            mid[n] = mfma16(ah, bl, mid[n]);
            mid[n] = mfma16(al, bh, mid[n]);
        }
    }
    #pragma unroll
    for (int n = 0; n < 8; ++n)
        #pragma unroll
        for (int r = 0; r < 4; ++r) {
            float comb = fmaf(mid[n][r], 4.8828125e-4f, hi[n][r]);
            const int img = mtile * 64 + w * 16 + g * 4 + r;
            part[((size_t)kchunk * 512 + img) * 128 + n * 16 + co] =
                __fmul_rn(comb, 1.52587890625e-5f);
        }
}

// ---------------- reduce partials + b1 + relu -> x0 [512,128] ----------------
__global__ __launch_bounds__(256) void k_reduce(const float* __restrict__ part,
                                                const float* __restrict__ b1,
                                                float* __restrict__ x0) {
    int t = blockIdx.x * 256 + threadIdx.x;  // 0..65535
    float s = b1[t & 127];
    for (int ch = 0; ch < 64; ++ch)
        s += part[(size_t)ch * 65536 + t];
    x0[t] = fmaxf(s, 0.f);
}

// ---------------- fused trunk + heads (+ folded vq-loss finalize) ----------------
__device__ __forceinline__ void mlp_layer(const float in[][16], float out[][16],
                                          const float* __restrict__ W,
                                          const float* __restrict__ bias,
                                          int tid, bool dorelu) {
    const int lane = tid & 63, wv = tid >> 6;
    const int img = lane & 15, cg = lane >> 4;
    const int c0 = wv * 32 + cg * 8;
    float acc[8] = {0,0,0,0,0,0,0,0};
    for (int k = 0; k < 128; ++k) {
        float a = in[k][img];
        float4 wA = *(const float4*)(W + (size_t)k * 128 + c0);
        float4 wB = *(const float4*)(W + (size_t)k * 128 + c0 + 4);
        acc[0] = fmaf(a, wA.x, acc[0]);
        acc[1] = fmaf(a, wA.y, acc[1]);
        acc[2] = fmaf(a, wA.z, acc[2]);
        acc[3] = fmaf(a, wA.w, acc[3]);
        acc[4] = fmaf(a, wB.x, acc[4]);
        acc[5] = fmaf(a, wB.y, acc[5]);
        acc[6] = fmaf(a, wB.z, acc[6]);
        acc[7] = fmaf(a, wB.w, acc[7]);
    }
    #pragma unroll
    for (int c = 0; c < 8; ++c) {
        float v = acc[c] + bias[c0 + c];
        if (dorelu) v = fmaxf(v, 0.f);
        out[c0 + c][img] = v;
    }
}

__global__ __launch_bounds__(256) void k_trunk(const float* __restrict__ x0,
        const float* __restrict__ w2, const float* __restrict__ b2,
        const float* __restrict__ w3, const float* __restrict__ b3,
        const float* __restrict__ wa1, const float* __restrict__ ba1,
        const float* __restrict__ wa2, const float* __restrict__ ba2,
        const float* __restrict__ wc1, const float* __restrict__ bc1,
        const float* __restrict__ wc2, const float* __restrict__ bc2,
        const float* __restrict__ wc3, const float* __restrict__ bc3,
        float* __restrict__ probs, float* __restrict__ value,
        const float* __restrict__ accv, float* __restrict__ vqloss) {
    __shared__ float bufA[128][16], bufB[128][16], bufC[128][16];
    __shared__ float lg[16][10];
    const int tid = threadIdx.x;
    const int m0 = blockIdx.x * 16;
    if (blockIdx.x == 0 && tid == 0)     // folded k_vqfinal (k_vq complete: stream order)
        vqloss[0] = accv[0] * 1.25f / 33554432.f;
    for (int r = 0; r < 2; ++r) {
        int j = tid + r * 256;                 // 0..511
        int img = j >> 5, k4 = j & 31;
        float4 v = *(const float4*)(x0 + (size_t)(m0 + img) * 128 + k4 * 4);
        bufA[k4*4+0][img] = v.x;
        bufA[k4*4+1][img] = v.y;
        bufA[k4*4+2][img] = v.z;
        bufA[k4*4+3][img] = v.w;
    }
    __syncthreads();
    mlp_layer(bufA, bufB, w2, b2, tid, true);   __syncthreads();
    mlp_layer(bufB, bufC, w3, b3, tid, true);   __syncthreads();  // C = e3
    mlp_layer(bufC, bufA, wa1, ba1, tid, true); __syncthreads();  // A = a1
    if (tid < 160) {
        int img = tid & 15, col = tid >> 4;     // col 0..9
        float s = 0.f;
        for (int k = 0; k < 128; ++k)
            s = fmaf(bufA[k][img], wa2[(size_t)k * 10 + col], s);
        lg[img][col] = s + ba2[col];
    }
    __syncthreads();
    if (tid < 16) {
        int img = tid;
        float m = lg[img][0];
        #pragma unroll
        for (int c = 1; c < 10; ++c) m = fmaxf(m, lg[img][c]);
        float e[10]; float s = 0.f;
        #pragma unroll
        for (int c = 0; c < 10; ++c) { e[c] = expf(lg[img][c] - m); s += e[c]; }
        float inv = 1.f / s;
        #pragma unroll
        for (int c = 0; c < 10; ++c)
            probs[(size_t)(m0 + img) * 10 + c] = e[c] * inv;
    }
    __syncthreads();
    mlp_layer(bufC, bufB, wc1, bc1, tid, true); __syncthreads();
    mlp_layer(bufB, bufA, wc2, bc2, tid, true); __syncthreads();  // A = c2
    if (tid < 16) {
        int img = tid;
        float s = 0.f;
        for (int k = 0; k < 128; ++k)
            s = fmaf(bufA[k][img], wc3[k], s);
        value[m0 + img] = s + bc3[0];
    }
}

extern "C" void kernel_launch(void* const* d_in, const int* in_sizes, int n_in,
                              void* d_out, int out_size, void* d_ws, size_t ws_size,
                              hipStream_t stream) {
    const float* x   = (const float*)d_in[0];
    const float* c1w = (const float*)d_in[1];
    const float* c1b = (const float*)d_in[2];
    const float* c2w = (const float*)d_in[3];
    const float* c2b = (const float*)d_in[4];
    const float* cb  = (const float*)d_in[5];
    const float* w1  = (const float*)d_in[6];
    const float* b1  = (const float*)d_in[7];
    const float* w2  = (const float*)d_in[8];
    const float* b2  = (const float*)d_in[9];
    const float* w3  = (const float*)d_in[10];
    const float* b3  = (const float*)d_in[11];
    const float* wa1 = (const float*)d_in[12];
    const float* ba1 = (const float*)d_in[13];
    const float* wa2 = (const float*)d_in[14];
    const float* ba2 = (const float*)d_in[15];
    const float* wc1 = (const float*)d_in[16];
    const float* bc1 = (const float*)d_in[17];
    const float* wc2 = (const float*)d_in[18];
    const float* bc2 = (const float*)d_in[19];
    const float* wc3 = (const float*)d_in[20];
    const float* bc3 = (const float*)d_in[21];

    float* out = (float*)d_out;
    float* ws  = (float*)d_ws;

    // workspace layout (floats):
    float* h1    = ws;                                   // 16,777,216  (live until k_vq done)
    float* part  = ws;                                   //  4,194,304  (reuses h1, post-k_vq)
    float* x0    = ws + (size_t)4 * 1024 * 1024;         //     65,536  (inside dead h1)
    float* h     = ws + (size_t)16 * 1024 * 1024;        // 33,554,432  (dead after k_vq)
    hf*    w1Th  = (hf*)(ws + (size_t)16777216);         //  8,388,608 hf (in dead h)
    hf*    w1Tl  = (hf*)(ws + (size_t)20971520);         //  8,388,608 hf (in dead h)
    int*   idxw  = (int*)(ws + (size_t)50331648);        //    524,288 ints
    float* cn    = ws + (size_t)50855936;                //        512
    float* accv  = ws + (size_t)50856448;                //          1
    hf*    cbh   = (hf*)(ws + (size_t)50857984);         //     32,768 f16
    hf*    cbl   = (hf*)(ws + (size_t)50874368);         //     32,768 f16
    hf*    wTh   = (hf*)(ws + (size_t)50890752);         //     18,432 f16
    hf*    wTl   = (hf*)(ws + (size_t)50899968);         //     18,432 f16

    hipLaunchKernelGGL(k_conv1,  dim3(512),   dim3(256), 0, stream, x, c1w, c1b, h1,
                       cb, c2w, cn, cbh, cbl, wTh, wTl, accv);
    hipLaunchKernelGGL(k_conv2,  dim3(2048),  dim3(512), 0, stream, h1, wTh, wTl,
                       c2b, h);
    hipLaunchKernelGGL(k_vq,     dim3(2048),  dim3(512), 0, stream, h, h1, c2w, c2b,
                       cb, cbh, cbl, cn, idxw, out + 5633, accv);
    hipLaunchKernelGGL(k_prepw1, dim3(4096),  dim3(256), 0, stream, w1, w1Th, w1Tl);
    hipLaunchKernelGGL(k_fc1,    dim3(64, 8), dim3(256), 0, stream, idxw, cbh, cbl,
                       w1Th, w1Tl, part);
    hipLaunchKernelGGL(k_reduce, dim3(256),   dim3(256), 0, stream, part, b1, x0);
    hipLaunchKernelGGL(k_trunk,  dim3(32),    dim3(256), 0, stream, x0,
                       w2, b2, w3, b3, wa1, ba1, wa2, ba2,
                       wc1, bc1, wc2, bc2, wc3, bc3,
                       out, out + 5120, accv, out + 5632);
}

// Round 12
// 710.695 us; speedup vs baseline: 1.0434x; 1.0434x over previous
//
#include <hip/hip_runtime.h>
#include <math.h>

#define NB 512
#define DD 32
#define NPX 1024      // 32*32
#define NTOT 524288   // 512*1024
#define NC 512
#define CD 64

typedef float v2f __attribute__((ext_vector_type(2)));
typedef _Float16 hf;
typedef hf hf8 __attribute__((ext_vector_type(8)));
typedef float f32x4 __attribute__((ext_vector_type(4)));

__device__ __forceinline__ v2f pkfma(v2f a, v2f b, v2f c) {
    return __builtin_elementwise_fma(a, b, c);
}
__device__ __forceinline__ v2f splat2(float s) { v2f r; r.x = s; r.y = s; return r; }

__device__ __forceinline__ f32x4 mfma16(hf8 a, hf8 b, f32x4 c) {
    return __builtin_amdgcn_mfma_f32_16x16x32_f16(a, b, c, 0, 0, 0);
}

// numpy pairwise-8 sum of squares over 64 contiguous elements.
__device__ __forceinline__ float np_sumsq64(const float* a, int stride) {
    float r[8];
    #pragma unroll
    for (int j = 0; j < 8; ++j) {
        float v = a[j * stride];
        r[j] = __fmul_rn(v, v);
    }
    #pragma unroll
    for (int i = 1; i < 8; ++i)
        #pragma unroll
        for (int j = 0; j < 8; ++j) {
            float v = a[(i * 8 + j) * stride];
            r[j] = __fadd_rn(r[j], __fmul_rn(v, v));
        }
    return __fadd_rn(__fadd_rn(__fadd_rn(r[0], r[1]), __fadd_rn(r[2], r[3])),
                     __fadd_rn(__fadd_rn(r[4], r[5]), __fadd_rn(r[6], r[7])));
}

// ---------------- conv1 (+ folded init: cnorm, cb-split, w2-split-transpose) ----------------
__global__ __launch_bounds__(256) void k_conv1(const float* __restrict__ x,
                                               const float* __restrict__ w,
                                               const float* __restrict__ bias,
                                               float* __restrict__ h1,
                                               const float* __restrict__ cb,
                                               const float* __restrict__ c2w,
                                               float* __restrict__ cnorm,
                                               hf* __restrict__ cbh,
                                               hf* __restrict__ cbl,
                                               hf* __restrict__ wTh,
                                               hf* __restrict__ wTl,
                                               float* __restrict__ accv) {
    const int b = blockIdx.x;
    const int tid = threadIdx.x;
    {   // folded side work on low blocks (independent of conv)
        int t = b * 256 + tid;
        if (t < NC)
            cnorm[t] = np_sumsq64(cb + (size_t)t * CD, 1);
        if (b < 128) {   // t < 32768: split codebook into scaled f16 hi/lo
            float a = cb[t] * 256.f;             // exact pow2 scale
            hf h0 = (hf)a;
            float rl = (a - (float)h0) * 2048.f; // exact (Sterbenz + pow2)
            cbh[t] = h0;
            cbl[t] = (hf)rl;
        }
        if (b >= 128 && b < 200) {   // split+transpose conv2 weights: wT[s9][co][ci]
            int t2 = (b - 128) * 256 + tid;
            if (t2 < 18432) {
                int s9 = t2 >> 11, rem = t2 & 2047;
                int co = rem >> 5, ci = rem & 31;
                float a = c2w[s9 * 2048 + ci * 64 + co] * 256.f;
                hf h0 = (hf)a;
                float rl = (a - (float)h0) * 2048.f;
                wTh[t2] = h0;    // t2 = (s9*64+co)*32 + ci
                wTl[t2] = (hf)rl;
            }
        }
        if (t == 0) accv[0] = 0.f;
    }
    __shared__ float xs[34][34];
    for (int i = tid; i < 34 * 34; i += 256) {
        int yy = i / 34, xx = i - yy * 34;
        float v = 0.f;
        if (yy >= 1 && yy <= 32 && xx >= 1 && xx <= 32)
            v = x[(size_t)b * NPX + (yy - 1) * 32 + (xx - 1)];
        xs[yy][xx] = v;
    }
    __syncthreads();
    for (int rep = 0; rep < 4; ++rep) {
        int px = tid + rep * 256;
        int y = px >> 5, xc = px & 31;
        v2f acc2[16];
        #pragma unroll
        for (int c = 0; c < 16; ++c) acc2[c] = splat2(0.f);
        #pragma unroll
        for (int dy = 0; dy < 3; ++dy)
        #pragma unroll
        for (int dx = 0; dx < 3; ++dx) {
            float a = xs[y + dy][xc + dx];
            v2f av = splat2(a);
            const v2f* wr = (const v2f*)(w + (dy * 3 + dx) * 32);
            #pragma unroll
            for (int c = 0; c < 16; ++c) acc2[c] = pkfma(av, wr[c], acc2[c]);
        }
        float4* out = (float4*)(h1 + ((size_t)b * NPX + px) * 32);
        #pragma unroll
        for (int q = 0; q < 8; ++q) {
            float4 v;
            v.x = fmaxf(__fadd_rn(acc2[q*2+0].x, bias[q*4+0]), 0.f);
            v.y = fmaxf(__fadd_rn(acc2[q*2+0].y, bias[q*4+1]), 0.f);
            v.z = fmaxf(__fadd_rn(acc2[q*2+1].x, bias[q*4+2]), 0.f);
            v.w = fmaxf(__fadd_rn(acc2[q*2+1].y, bias[q*4+3]), 0.f);
            out[q] = v;
        }
    }
}

// ---------------- conv2 via 4-term split-f16 MFMA (R9 passing version) ----------------
#define CI_P 40
__global__ __launch_bounds__(512, 4) void k_conv2(const float* __restrict__ h1,
                                                  const hf* __restrict__ wTh,
                                                  const hf* __restrict__ wTl,
                                                  const float* __restrict__ bias,
                                                  float* __restrict__ h) {
    __shared__ hf Ah[10 * 34 * CI_P];   // 27.2 KB
    __shared__ hf Al[10 * 34 * CI_P];   // 27.2 KB
    const int blk = blockIdx.x;
    const int b = blk >> 2, strip = blk & 3;
    const int r0 = strip * 8;
    const int tid = threadIdx.x;
    for (int i = tid; i < 640; i += 512) {   // zero-pad x columns 0 and 33
        int ci = i & 31, rem = i >> 5;       // rem 0..19
        int ry = rem >> 1, colx = (rem & 1) * 33;
        int idx = (ry * 34 + colx) * CI_P + ci;
        Ah[idx] = (hf)0.f;
        Al[idx] = (hf)0.f;
    }
    #pragma unroll
    for (int r = 0; r < 5; ++r) {        // 2560 float4 = 10 rows x 32x x 8ci4
        int j = tid + r * 512;
        int ci4 = j & 7, xc = (j >> 3) & 31, ry = j >> 8;   // ry 0..9
        int gy = r0 - 1 + ry;
        float4 v = make_float4(0.f, 0.f, 0.f, 0.f);
        if (gy >= 0 && gy < 32)
            v = *(const float4*)(h1 + ((size_t)b * NPX + gy * 32 + xc) * 32 + ci4 * 4);
        int bi = (ry * 34 + xc + 1) * CI_P + ci4 * 4;
        float fv[4] = {v.x, v.y, v.z, v.w};
        #pragma unroll
        for (int q = 0; q < 4; ++q) {
            float a = fv[q] * 256.f;               // exact pow2 scale
            hf h0 = (hf)a;
            float rl = (a - (float)h0) * 2048.f;   // exact
            Ah[bi + q] = h0;
            Al[bi + q] = (hf)rl;
        }
    }
    __syncthreads();
    const int w = tid >> 6, l = tid & 63;   // wave w owns strip-row w (32 px)
    const int i16 = l & 15, j4 = l >> 4;
    #pragma unroll 1
    for (int ntp = 0; ntp < 2; ++ntp) {     // N-tile pairs: co [0,32), [32,64)
        f32x4 hi[2][2], mid[2][2], llt[2][2];   // [m-subtile][ntl]
        #pragma unroll
        for (int s = 0; s < 2; ++s)
            #pragma unroll
            for (int n = 0; n < 2; ++n) {
                hi[s][n] = f32x4{0.f, 0.f, 0.f, 0.f};
                mid[s][n] = f32x4{0.f, 0.f, 0.f, 0.f};
                llt[s][n] = f32x4{0.f, 0.f, 0.f, 0.f};
            }
        #pragma unroll 1
        for (int s9 = 0; s9 < 9; ++s9) {
            const int dy = s9 / 3, dx = s9 - dy * 3;
            hf8 a_h[2], a_l[2];
            #pragma unroll
            for (int s = 0; s < 2; ++s) {
                int ofs = ((w + dy) * 34 + (s * 16 + i16 + dx)) * CI_P + 8 * j4;
                a_h[s] = *(const hf8*)(Ah + ofs);
                a_l[s] = *(const hf8*)(Al + ofs);
            }
            #pragma unroll
            for (int ntl = 0; ntl < 2; ++ntl) {
                const int nt = ntp * 2 + ntl;
                const int wofs = (s9 * 64 + nt * 16 + i16) * 32 + 8 * j4;
                const hf8 b_h = *(const hf8*)(wTh + wofs);
                const hf8 b_l = *(const hf8*)(wTl + wofs);
                #pragma unroll
                for (int s = 0; s < 2; ++s) {
                    hi[s][ntl]  = mfma16(a_h[s], b_h, hi[s][ntl]);
                    mid[s][ntl] = mfma16(a_h[s], b_l, mid[s][ntl]);
                    mid[s][ntl] = mfma16(a_l[s], b_h, mid[s][ntl]);
                    llt[s][ntl] = mfma16(a_l[s], b_l, llt[s][ntl]);
                }
            }
        }
        #pragma unroll
        for (int ntl = 0; ntl < 2; ++ntl) {
            const int co = (ntp * 2 + ntl) * 16 + i16;
            const float bco = bias[co];
            #pragma unroll
            for (int s = 0; s < 2; ++s) {
                #pragma unroll
                for (int r = 0; r < 4; ++r) {
                    float comb = fmaf(mid[s][ntl][r], 4.8828125e-4f,
                                 fmaf(llt[s][ntl][r], 2.384185791015625e-7f,
                                      hi[s][ntl][r]));
                    float hv = fmaxf(
                        __fadd_rn(__fmul_rn(comb, 1.52587890625e-5f), bco), 0.f);
                    int px = w * 32 + s * 16 + j4 * 4 + r;
                    h[((size_t)b * NPX + r0 * 32 + px) * 64 + co] = hv;
                }
            }
        }
    }
}

// ---------------- VQ: 3-term split-f16 MFMA screener + wave-local certified rescue ----------------
// Screener tracks d' = cn - (2/65536)*dot (per-pixel constant H dropped: argmin and the
// top-2 gap are invariant to it). 3-term split error B ~1-2e-5 << TAU/2 (TAU=2e-4, >=5x
// margin; R5 precedent passed 3-term@1e-3, R7 passed 2-term@5e-4). Gap > TAU certifies
// approx winner = exact fp32 winner. Gap <= TAU -> ONE WAVE recomputes that pixel's h
// EXACTLY (R12 chain from h1) -> exact H -> exact 512 distances -> numpy first-occurrence.
// Rescues are distributed rr%8==wave, fully wave-local (no barriers): lane l does co=l for
// the conv chain (coalesced c2w), then codes 8l..8l+7 (in-lane ascending strict <) and a
// lexicographic (v,idx) shuffle reduce.
#define TAU 2e-4f
__global__ __launch_bounds__(512, 4) void k_vq(const float* __restrict__ h,
                                               const float* __restrict__ h1,
                                               const float* __restrict__ c2w,
                                               const float* __restrict__ c2b,
                                               const float* __restrict__ cb,
                                               const hf* __restrict__ cbh,
                                               const hf* __restrict__ cbl,
                                               const float* __restrict__ cnorm,
                                               int* __restrict__ idxout,
                                               float* __restrict__ fidx,
                                               float* __restrict__ lossacc) {
    __shared__ float4 Ats[16][256];   // 64 KB
    __shared__ float cn_lds[512];
    __shared__ int   mis_lds[256];
    __shared__ int   rlist[256];
    __shared__ float hex[8][64];      // per-wave exact-h scratch
    __shared__ int   rcnt;
    const int tid = threadIdx.x;
    const size_t base = (size_t)blockIdx.x * 256;
    if (tid == 0) rcnt = 0;
    {   // stage h rows
        const int px = tid & 255, half = tid >> 8;
        const float4* src = (const float4*)(h + (base + px) * 64 + half * 32);
        #pragma unroll
        for (int j = 0; j < 8; ++j)
            Ats[half * 8 + j][px] = src[j];
    }
    cn_lds[tid] = cnorm[tid];
    __syncthreads();
    const int w = tid >> 6, l = tid & 63;
    const int co = l & 15, g = l >> 4;
    const int pxw = w * 32;
    hf8 ah[2][2], al[2][2];
    #pragma unroll
    for (int s = 0; s < 2; ++s)
        #pragma unroll
        for (int ks = 0; ks < 2; ++ks) {
            float4 q0 = Ats[ks * 8 + g * 2 + 0][pxw + s * 16 + co];
            float4 q1 = Ats[ks * 8 + g * 2 + 1][pxw + s * 16 + co];
            float fv[8] = {q0.x, q0.y, q0.z, q0.w, q1.x, q1.y, q1.z, q1.w};
            #pragma unroll
            for (int j = 0; j < 8; ++j) {
                float fa = fv[j] * 256.f;
                hf h0 = (hf)fa;
                float rl = (fa - (float)h0) * 2048.f;
                ah[s][ks][j] = h0;
                al[s][ks][j] = (hf)rl;
            }
        }
    float minv[2][4], min2[2][4];
    int   mini[2][4];
    #pragma unroll
    for (int s = 0; s < 2; ++s)
        #pragma unroll
        for (int r = 0; r < 4; ++r) {
            minv[s][r] = 3.4e38f; min2[s][r] = 3.4e38f; mini[s][r] = 0;
        }
    const hf* pbh = cbh + (size_t)co * 64 + g * 8;
    const hf* pbl = cbl + (size_t)co * 64 + g * 8;
    #pragma unroll 1
    for (int t = 0; t < 32; ++t) {
        const hf8 bh0 = *(const hf8*)(pbh + (size_t)t * 1024);
        const hf8 bh1 = *(const hf8*)(pbh + (size_t)t * 1024 + 32);
        const hf8 bl0 = *(const hf8*)(pbl + (size_t)t * 1024);
        const hf8 bl1 = *(const hf8*)(pbl + (size_t)t * 1024 + 32);
        const float cn = cn_lds[t * 16 + co];
        #pragma unroll
        for (int s = 0; s < 2; ++s) {
            f32x4 hi = {0.f, 0.f, 0.f, 0.f};
            f32x4 lo = {0.f, 0.f, 0.f, 0.f};
            f32x4 ll = {0.f, 0.f, 0.f, 0.f};
            lo = mfma16(ah[s][0], bl0, lo);
            lo = mfma16(al[s][0], bh0, lo);
            ll = mfma16(al[s][0], bl0, ll);
            hi = mfma16(ah[s][0], bh0, hi);
            lo = mfma16(ah[s][1], bl1, lo);
            lo = mfma16(al[s][1], bh1, lo);
            ll = mfma16(al[s][1], bl1, ll);
            hi = mfma16(ah[s][1], bh1, hi);
            #pragma unroll
            for (int r = 0; r < 4; ++r) {
                float comb = fmaf(lo[r], 4.8828125e-4f,
                             fmaf(ll[r], 2.384185791015625e-7f, hi[r]));
                float d = __fsub_rn(cn, __fmul_rn(3.0517578125e-5f, comb));
                if (d < minv[s][r]) {
                    min2[s][r] = minv[s][r];
                    minv[s][r] = d; mini[s][r] = t * 16 + co;
                } else if (d < min2[s][r]) {
                    min2[s][r] = d;
                }
            }
        }
    }
    #pragma unroll
    for (int s = 0; s < 2; ++s)
        #pragma unroll
        for (int r = 0; r < 4; ++r) {
            float v1 = minv[s][r], v2 = min2[s][r];
            int i1 = mini[s][r];
            #pragma unroll
            for (int off = 1; off < 16; off <<= 1) {
                float vo  = __shfl_xor(v1, off, 64);
                int   io  = __shfl_xor(i1, off, 64);
                float v2o = __shfl_xor(v2, off, 64);
                if (vo < v1 || (vo == v1 && io < i1)) {
                    v2 = fminf(v1, v2o);
                    v1 = vo; i1 = io;
                } else {
                    v2 = fminf(v2, vo);
                }
            }
            if (co == 0) {
                int pxo = pxw + s * 16 + g * 4 + r;
                mis_lds[pxo] = i1;
                if (v2 - v1 <= TAU) {
                    int slot = atomicAdd(&rcnt, 1);
                    rlist[slot] = pxo;
                }
            }
        }
    __syncthreads();
    // ---- certified exact rescue: wave-local, barrier-free, rr%8 == wave ----
    const int nresc = rcnt;
    for (int rr = w; rr < nresc; rr += 8) {
        const int px = rlist[rr];
        const int gpx = (int)base + px;
        const int bimg = gpx >> 10, pp = gpx & 1023;
        const int py = pp >> 5, pxx = pp & 31;
        float* hx = &hex[w][0];
        {   // lane l = co: exact conv2 chain (s9 asc, ci asc), coalesced c2w reads
            float acc = 0.f;
            #pragma unroll 1
            for (int s9 = 0; s9 < 9; ++s9) {
                const int dy = s9 / 3, dx = s9 - dy * 3;
                const int gy = py + dy - 1, gx = pxx + dx - 1;
                if (gy >= 0 && gy < 32 && gx >= 0 && gx < 32) {
                    const float* hp = h1 + ((size_t)bimg * NPX + gy * 32 + gx) * 32;
                    const float* wp = c2w + s9 * 2048 + l;
                    #pragma unroll
                    for (int ci = 0; ci < 32; ++ci)
                        acc = fmaf(hp[ci], wp[ci * 64], acc);
                }
            }
            hx[l] = fmaxf(__fadd_rn(acc, c2b[l]), 0.f);
        }
        // same-wave LDS write->read: compiler-inserted lgkmcnt wait, no barrier needed
        const float Hp = np_sumsq64(hx, 1);   // exact H (broadcast reads)
        float bv = 3.4e38f; int bi2 = 0;
        const float* crow = cb + (size_t)(l * 8) * 64;
        #pragma unroll 1
        for (int c = 0; c < 8; ++c) {         // in-lane codes ascending, strict <
            float acc0 = 0.f;
            const float* cr = crow + c * 64;
            #pragma unroll
            for (int kg = 0; kg < 16; ++kg) {
                acc0 = fmaf(hx[kg*4+0], cr[kg*4+0], acc0);
                acc0 = fmaf(hx[kg*4+1], cr[kg*4+1], acc0);
                acc0 = fmaf(hx[kg*4+2], cr[kg*4+2], acc0);
                acc0 = fmaf(hx[kg*4+3], cr[kg*4+3], acc0);
            }
            float d = __fadd_rn(__fsub_rn(Hp, __fmul_rn(2.f, acc0)),
                                cn_lds[l * 8 + c]);
            if (d < bv) { bv = d; bi2 = l * 8 + c; }
        }
        #pragma unroll
        for (int off = 1; off < 64; off <<= 1) {   // lexicographic (v,idx): first occurrence
            float vo = __shfl_xor(bv, off, 64);
            int   io = __shfl_xor(bi2, off, 64);
            if (vo < bv || (vo == bv && io < bi2)) { bv = vo; bi2 = io; }
        }
        if (l == 0) mis_lds[px] = bi2;
    }
    __syncthreads();
    // ---- outputs + loss epilogue ----
    if (tid < 256) {
        int bi = mis_lds[tid];
        idxout[base + tid] = bi;
        fidx[base + tid] = (float)bi;
        float ls = 0.f;
        const float* crow = cb + (size_t)bi * 64;
        #pragma unroll
        for (int kg = 0; kg < 16; ++kg) {
            float4 a = Ats[kg][tid];
            float d0 = crow[kg*4+0] - a.x;
            float d1 = crow[kg*4+1] - a.y;
            float d2 = crow[kg*4+2] - a.z;
            float d3 = crow[kg*4+3] - a.w;
            ls = fmaf(d0, d0, ls); ls = fmaf(d1, d1, ls);
            ls = fmaf(d2, d2, ls); ls = fmaf(d3, d3, ls);
        }
        #pragma unroll
        for (int off = 32; off > 0; off >>= 1)
            ls += __shfl_down(ls, off, 64);
        if ((tid & 63) == 0) atomicAdd(lossacc, ls);
    }
}

// ---------------- prep w1: split + transpose into blocked [k8][128 n][8 k] hf ----------------
__global__ __launch_bounds__(256) void k_prepw1(const float* __restrict__ w1,
                                                hf* __restrict__ w1h,
                                                hf* __restrict__ w1l) {
    int t = blockIdx.x * 256 + threadIdx.x;  // 0..1048575
    int n = t & 127, k8 = t >> 7;            // k8 0..8191
    hf vh[8], vl[8];
    #pragma unroll
    for (int j = 0; j < 8; ++j) {
        float a = w1[(size_t)(k8 * 8 + j) * 128 + n] * 256.f;  // exact pow2 scale
        hf h0 = (hf)a;
        float rl = (a - (float)h0) * 2048.f;                   // exact
        vh[j] = h0;
        vl[j] = (hf)rl;
    }
    *(hf8*)(w1h + (size_t)k8 * 1024 + n * 8) = *(hf8*)vh;
    *(hf8*)(w1l + (size_t)k8 * 1024 + n * 8) = *(hf8*)vl;
}

// ---------------- fc1 via 3-term split-f16 MFMA: emb @ w1 -> K-split partials ----------------
__global__ __launch_bounds__(256) void k_fc1(const int* __restrict__ idxw,
                                             const hf* __restrict__ cbh,
                                             const hf* __restrict__ cbl,
                                             const hf* __restrict__ w1h,
                                             const hf* __restrict__ w1l,
                                             float* __restrict__ part) {
    const int kchunk = blockIdx.x;       // 0..63  (16 pixels = K 1024)
    const int mtile  = blockIdx.y;       // 0..7   (64 images)
    const int tid = threadIdx.x;
    const int w = tid >> 6, l = tid & 63;    // wave = 16-img subtile
    const int co = l & 15, g = l >> 4;
    const int mbase = mtile * 64 + w * 16;
    f32x4 hi[8], mid[8];
    #pragma unroll
    for (int n = 0; n < 8; ++n) {
        hi[n] = f32x4{0.f, 0.f, 0.f, 0.f};
        mid[n] = f32x4{0.f, 0.f, 0.f, 0.f};
    }
    int code = 0;
    #pragma unroll 1
    for (int kstep = 0; kstep < 32; ++kstep) {   // 32 x K=32
        if ((kstep & 1) == 0) {
            const int pix = kchunk * 16 + (kstep >> 1);
            code = idxw[(size_t)(mbase + co) * NPX + pix];
        }
        const int koff = (kstep & 1) * 32 + g * 8;
        const hf8 ah = *(const hf8*)(cbh + ((size_t)code << 6) + koff);
        const hf8 al = *(const hf8*)(cbl + ((size_t)code << 6) + koff);
        const size_t k8b = (size_t)(kchunk * 128 + kstep * 4 + g) * 1024;
        #pragma unroll
        for (int n = 0; n < 8; ++n) {
            const hf8 bh = *(const hf8*)(w1h + k8b + (n * 16 + co) * 8);
            const hf8 bl = *(const hf8*)(w1l + k8b + (n * 16 + co) * 8);
            hi[n]  = mfma16(ah, bh, hi[n]);
            mid[n] = mfma16(ah, bl, mid[n]);
            mid[n] = mfma16(al, bh, mid[n]);
        }
    }
    #pragma unroll
    for (int n = 0; n < 8; ++n)
        #pragma unroll
        for (int r = 0; r < 4; ++r) {
            float comb = fmaf(mid[n][r], 4.8828125e-4f, hi[n][r]);
            const int img = mtile * 64 + w * 16 + g * 4 + r;
            part[((size_t)kchunk * 512 + img) * 128 + n * 16 + co] =
                __fmul_rn(comb, 1.52587890625e-5f);
        }
}

// ---------------- reduce partials + b1 + relu -> x0 [512,128] ----------------
__global__ __launch_bounds__(256) void k_reduce(const float* __restrict__ part,
                                                const float* __restrict__ b1,
                                                float* __restrict__ x0) {
    int t = blockIdx.x * 256 + threadIdx.x;  // 0..65535
    float s = b1[t & 127];
    for (int ch = 0; ch < 64; ++ch)
        s += part[(size_t)ch * 65536 + t];
    x0[t] = fmaxf(s, 0.f);
}

// ---------------- fused trunk + heads (+ folded vq-loss finalize) ----------------
__device__ __forceinline__ void mlp_layer(const float in[][16], float out[][16],
                                          const float* __restrict__ W,
                                          const float* __restrict__ bias,
                                          int tid, bool dorelu) {
    const int lane = tid & 63, wv = tid >> 6;
    const int img = lane & 15, cg = lane >> 4;
    const int c0 = wv * 32 + cg * 8;
    float acc[8] = {0,0,0,0,0,0,0,0};
    for (int k = 0; k < 128; ++k) {
        float a = in[k][img];
        float4 wA = *(const float4*)(W + (size_t)k * 128 + c0);
        float4 wB = *(const float4*)(W + (size_t)k * 128 + c0 + 4);
        acc[0] = fmaf(a, wA.x, acc[0]);
        acc[1] = fmaf(a, wA.y, acc[1]);
        acc[2] = fmaf(a, wA.z, acc[2]);
        acc[3] = fmaf(a, wA.w, acc[3]);
        acc[4] = fmaf(a, wB.x, acc[4]);
        acc[5] = fmaf(a, wB.y, acc[5]);
        acc[6] = fmaf(a, wB.z, acc[6]);
        acc[7] = fmaf(a, wB.w, acc[7]);
    }
    #pragma unroll
    for (int c = 0; c < 8; ++c) {
        float v = acc[c] + bias[c0 + c];
        if (dorelu) v = fmaxf(v, 0.f);
        out[c0 + c][img] = v;
    }
}

__global__ __launch_bounds__(256) void k_trunk(const float* __restrict__ x0,
        const float* __restrict__ w2, const float* __restrict__ b2,
        const float* __restrict__ w3, const float* __restrict__ b3,
        const float* __restrict__ wa1, const float* __restrict__ ba1,
        const float* __restrict__ wa2, const float* __restrict__ ba2,
        const float* __restrict__ wc1, const float* __restrict__ bc1,
        const float* __restrict__ wc2, const float* __restrict__ bc2,
        const float* __restrict__ wc3, const float* __restrict__ bc3,
        float* __restrict__ probs, float* __restrict__ value,
        const float* __restrict__ accv, float* __restrict__ vqloss) {
    __shared__ float bufA[128][16], bufB[128][16], bufC[128][16];
    __shared__ float lg[16][10];
    const int tid = threadIdx.x;
    const int m0 = blockIdx.x * 16;
    if (blockIdx.x == 0 && tid == 0)     // folded k_vqfinal (k_vq complete: stream order)
        vqloss[0] = accv[0] * 1.25f / 33554432.f;
    for (int r = 0; r < 2; ++r) {
        int j = tid + r * 256;                 // 0..511
        int img = j >> 5, k4 = j & 31;
        float4 v = *(const float4*)(x0 + (size_t)(m0 + img) * 128 + k4 * 4);
        bufA[k4*4+0][img] = v.x;
        bufA[k4*4+1][img] = v.y;
        bufA[k4*4+2][img] = v.z;
        bufA[k4*4+3][img] = v.w;
    }
    __syncthreads();
    mlp_layer(bufA, bufB, w2, b2, tid, true);   __syncthreads();
    mlp_layer(bufB, bufC, w3, b3, tid, true);   __syncthreads();  // C = e3
    mlp_layer(bufC, bufA, wa1, ba1, tid, true); __syncthreads();  // A = a1
    if (tid < 160) {
        int img = tid & 15, col = tid >> 4;     // col 0..9
        float s = 0.f;
        for (int k = 0; k < 128; ++k)
            s = fmaf(bufA[k][img], wa2[(size_t)k * 10 + col], s);
        lg[img][col] = s + ba2[col];
    }
    __syncthreads();
    if (tid < 16) {
        int img = tid;
        float m = lg[img][0];
        #pragma unroll
        for (int c = 1; c < 10; ++c) m = fmaxf(m, lg[img][c]);
        float e[10]; float s = 0.f;
        #pragma unroll
        for (int c = 0; c < 10; ++c) { e[c] = expf(lg[img][c] - m); s += e[c]; }
        float inv = 1.f / s;
        #pragma unroll
        for (int c = 0; c < 10; ++c)
            probs[(size_t)(m0 + img) * 10 + c] = e[c] * inv;
    }
    __syncthreads();
    mlp_layer(bufC, bufB, wc1, bc1, tid, true); __syncthreads();
    mlp_layer(bufB, bufA, wc2, bc2, tid, true); __syncthreads();  // A = c2
    if (tid < 16) {
        int img = tid;
        float s = 0.f;
        for (int k = 0; k < 128; ++k)
            s = fmaf(bufA[k][img], wc3[k], s);
        value[m0 + img] = s + bc3[0];
    }
}

extern "C" void kernel_launch(void* const* d_in, const int* in_sizes, int n_in,
                              void* d_out, int out_size, void* d_ws, size_t ws_size,
                              hipStream_t stream) {
    const float* x   = (const float*)d_in[0];
    const float* c1w = (const float*)d_in[1];
    const float* c1b = (const float*)d_in[2];
    const float* c2w = (const float*)d_in[3];
    const float* c2b = (const float*)d_in[4];
    const float* cb  = (const float*)d_in[5];
    const float* w1  = (const float*)d_in[6];
    const float* b1  = (const float*)d_in[7];
    const float* w2  = (const float*)d_in[8];
    const float* b2  = (const float*)d_in[9];
    const float* w3  = (const float*)d_in[10];
    const float* b3  = (const float*)d_in[11];
    const float* wa1 = (const float*)d_in[12];
    const float* ba1 = (const float*)d_in[13];
    const float* wa2 = (const float*)d_in[14];
    const float* ba2 = (const float*)d_in[15];
    const float* wc1 = (const float*)d_in[16];
    const float* bc1 = (const float*)d_in[17];
    const float* wc2 = (const float*)d_in[18];
    const float* bc2 = (const float*)d_in[19];
    const float* wc3 = (const float*)d_in[20];
    const float* bc3 = (const float*)d_in[21];

    float* out = (float*)d_out;
    float* ws  = (float*)d_ws;

    // workspace layout (floats):
    float* h1    = ws;                                   // 16,777,216  (live until k_vq done)
    float* part  = ws;                                   //  4,194,304  (reuses h1, post-k_vq)
    float* x0    = ws + (size_t)4 * 1024 * 1024;         //     65,536  (inside dead h1)
    float* h     = ws + (size_t)16 * 1024 * 1024;        // 33,554,432  (dead after k_vq)
    hf*    w1Th  = (hf*)(ws + (size_t)16777216);         //  8,388,608 hf (in dead h)
    hf*    w1Tl  = (hf*)(ws + (size_t)20971520);         //  8,388,608 hf (in dead h)
    int*   idxw  = (int*)(ws + (size_t)50331648);        //    524,288 ints
    float* cn    = ws + (size_t)50855936;                //        512
    float* accv  = ws + (size_t)50856448;                //          1
    hf*    cbh   = (hf*)(ws + (size_t)50857984);         //     32,768 f16
    hf*    cbl   = (hf*)(ws + (size_t)50874368);         //     32,768 f16
    hf*    wTh   = (hf*)(ws + (size_t)50890752);         //     18,432 f16
    hf*    wTl   = (hf*)(ws + (size_t)50899968);         //     18,432 f16

    hipLaunchKernelGGL(k_conv1,  dim3(512),   dim3(256), 0, stream, x, c1w, c1b, h1,
                       cb, c2w, cn, cbh, cbl, wTh, wTl, accv);
    hipLaunchKernelGGL(k_conv2,  dim3(2048),  dim3(512), 0, stream, h1, wTh, wTl,
                       c2b, h);
    hipLaunchKernelGGL(k_vq,     dim3(2048),  dim3(512), 0, stream, h, h1, c2w, c2b,
                       cb, cbh, cbl, cn, idxw, out + 5633, accv);
    hipLaunchKernelGGL(k_prepw1, dim3(4096),  dim3(256), 0, stream, w1, w1Th, w1Tl);
    hipLaunchKernelGGL(k_fc1,    dim3(64, 8), dim3(256), 0, stream, idxw, cbh, cbl,
                       w1Th, w1Tl, part);
    hipLaunchKernelGGL(k_reduce, dim3(256),   dim3(256), 0, stream, part, b1, x0);
    hipLaunchKernelGGL(k_trunk,  dim3(32),    dim3(256), 0, stream, x0,
                       w2, b2, w3, b3, wa1, ba1, wa2, ba2,
                       wc1, bc1, wc2, bc2, wc3, bc3,
                       out, out + 5120, accv, out + 5632);
}

// Round 13
// 710.533 us; speedup vs baseline: 1.0436x; 1.0002x over previous
//
#include <hip/hip_runtime.h>
#include <math.h>

#define NB 512
#define DD 32
#define NPX 1024      // 32*32
#define NTOT 524288   // 512*1024
#define NC 512
#define CD 64

typedef float v2f __attribute__((ext_vector_type(2)));
typedef _Float16 hf;
typedef hf hf8 __attribute__((ext_vector_type(8)));
typedef float f32x4 __attribute__((ext_vector_type(4)));

__device__ __forceinline__ v2f pkfma(v2f a, v2f b, v2f c) {
    return __builtin_elementwise_fma(a, b, c);
}
__device__ __forceinline__ v2f splat2(float s) { v2f r; r.x = s; r.y = s; return r; }

__device__ __forceinline__ f32x4 mfma16(hf8 a, hf8 b, f32x4 c) {
    return __builtin_amdgcn_mfma_f32_16x16x32_f16(a, b, c, 0, 0, 0);
}

// numpy pairwise-8 sum of squares over 64 contiguous elements.
__device__ __forceinline__ float np_sumsq64(const float* a, int stride) {
    float r[8];
    #pragma unroll
    for (int j = 0; j < 8; ++j) {
        float v = a[j * stride];
        r[j] = __fmul_rn(v, v);
    }
    #pragma unroll
    for (int i = 1; i < 8; ++i)
        #pragma unroll
        for (int j = 0; j < 8; ++j) {
            float v = a[(i * 8 + j) * stride];
            r[j] = __fadd_rn(r[j], __fmul_rn(v, v));
        }
    return __fadd_rn(__fadd_rn(__fadd_rn(r[0], r[1]), __fadd_rn(r[2], r[3])),
                     __fadd_rn(__fadd_rn(r[4], r[5]), __fadd_rn(r[6], r[7])));
}

// ---------------- conv1 (+ folded: cnorm, cb-split, w2-split-T, w1-split-T) ----------------
__global__ __launch_bounds__(256) void k_conv1(const float* __restrict__ x,
                                               const float* __restrict__ w,
                                               const float* __restrict__ bias,
                                               float* __restrict__ h1,
                                               const float* __restrict__ cb,
                                               const float* __restrict__ c2w,
                                               const float* __restrict__ w1,
                                               float* __restrict__ cnorm,
                                               hf* __restrict__ cbh,
                                               hf* __restrict__ cbl,
                                               hf* __restrict__ wTh,
                                               hf* __restrict__ wTl,
                                               hf* __restrict__ w1h,
                                               hf* __restrict__ w1l,
                                               float* __restrict__ accv) {
    const int b = blockIdx.x;
    const int tid = threadIdx.x;
    {   // folded side work on disjoint block ranges (independent of conv)
        int t = b * 256 + tid;
        if (t < NC)
            cnorm[t] = np_sumsq64(cb + (size_t)t * CD, 1);
        if (b < 128) {   // t < 32768: split codebook into scaled f16 hi/lo
            float a = cb[t] * 256.f;             // exact pow2 scale
            hf h0 = (hf)a;
            float rl = (a - (float)h0) * 2048.f; // exact (Sterbenz + pow2)
            cbh[t] = h0;
            cbl[t] = (hf)rl;
        }
        if (b >= 128 && b < 200) {   // split+transpose conv2 weights: wT[s9][co][ci]
            int t2 = (b - 128) * 256 + tid;
            if (t2 < 18432) {
                int s9 = t2 >> 11, rem = t2 & 2047;
                int co = rem >> 5, ci = rem & 31;
                float a = c2w[s9 * 2048 + ci * 64 + co] * 256.f;
                hf h0 = (hf)a;
                float rl = (a - (float)h0) * 2048.f;
                wTh[t2] = h0;    // t2 = (s9*64+co)*32 + ci
                wTl[t2] = (hf)rl;
            }
        }
        if (b >= 200 && b < 456) {   // split+block w1: w1T[k8][128 n][8 k] (was k_prepw1)
            int t3 = (b - 200) * 256 + tid;      // 0..65535
            int n = t3 & 127;
            int k8b = (t3 >> 7) * 16;            // 16 k8 rows per thread
            for (int kk = 0; kk < 16; ++kk) {
                int k8 = k8b + kk;
                hf vh[8], vl[8];
                #pragma unroll
                for (int j = 0; j < 8; ++j) {
                    float a = w1[(size_t)(k8 * 8 + j) * 128 + n] * 256.f;
                    hf h0 = (hf)a;
                    float rl = (a - (float)h0) * 2048.f;
                    vh[j] = h0;
                    vl[j] = (hf)rl;
                }
                *(hf8*)(w1h + (size_t)k8 * 1024 + n * 8) = *(hf8*)vh;
                *(hf8*)(w1l + (size_t)k8 * 1024 + n * 8) = *(hf8*)vl;
            }
        }
        if (t == 0) accv[0] = 0.f;
    }
    __shared__ float xs[34][34];
    for (int i = tid; i < 34 * 34; i += 256) {
        int yy = i / 34, xx = i - yy * 34;
        float v = 0.f;
        if (yy >= 1 && yy <= 32 && xx >= 1 && xx <= 32)
            v = x[(size_t)b * NPX + (yy - 1) * 32 + (xx - 1)];
        xs[yy][xx] = v;
    }
    __syncthreads();
    for (int rep = 0; rep < 4; ++rep) {
        int px = tid + rep * 256;
        int y = px >> 5, xc = px & 31;
        v2f acc2[16];
        #pragma unroll
        for (int c = 0; c < 16; ++c) acc2[c] = splat2(0.f);
        #pragma unroll
        for (int dy = 0; dy < 3; ++dy)
        #pragma unroll
        for (int dx = 0; dx < 3; ++dx) {
            float a = xs[y + dy][xc + dx];
            v2f av = splat2(a);
            const v2f* wr = (const v2f*)(w + (dy * 3 + dx) * 32);
            #pragma unroll
            for (int c = 0; c < 16; ++c) acc2[c] = pkfma(av, wr[c], acc2[c]);
        }
        float4* out = (float4*)(h1 + ((size_t)b * NPX + px) * 32);
        #pragma unroll
        for (int q = 0; q < 8; ++q) {
            float4 v;
            v.x = fmaxf(__fadd_rn(acc2[q*2+0].x, bias[q*4+0]), 0.f);
            v.y = fmaxf(__fadd_rn(acc2[q*2+0].y, bias[q*4+1]), 0.f);
            v.z = fmaxf(__fadd_rn(acc2[q*2+1].x, bias[q*4+2]), 0.f);
            v.w = fmaxf(__fadd_rn(acc2[q*2+1].y, bias[q*4+3]), 0.f);
            out[q] = v;
        }
    }
}

// ---------------- FUSED conv2 + VQ ----------------
// Phase 1 (R9 conv2, verbatim arithmetic): 4-term split-f16 MFMA conv2; epilogue writes
// hv into Ats[kg][px] LDS instead of global h (same f32 values bit-for-bit -> screener,
// argmin, loss identical to R12). Phase 2 (R12 k_vq verbatim): 3-term screener on d' =
// cn - (2/65536)*dot, top-2 gap certificate (TAU=2e-4 >> 2B), wave-local exact rescue
// from h1 (still live). Block mapping identical on both sides: blk=(b,strip) covers
// global px [blk*256, blk*256+256).
#define CI_P 40
#define TAU 2e-4f
__global__ __launch_bounds__(512, 2) void k_cvq(const float* __restrict__ h1,
                                                const hf* __restrict__ wTh,
                                                const hf* __restrict__ wTl,
                                                const float* __restrict__ c2w,
                                                const float* __restrict__ c2b,
                                                const float* __restrict__ cb,
                                                const hf* __restrict__ cbh,
                                                const hf* __restrict__ cbl,
                                                const float* __restrict__ cnorm,
                                                int* __restrict__ idxout,
                                                float* __restrict__ fidx,
                                                float* __restrict__ lossacc) {
    __shared__ hf Ah[10 * 34 * CI_P];   // 27.2 KB
    __shared__ hf Al[10 * 34 * CI_P];   // 27.2 KB
    __shared__ float4 Ats[16][256];     // 64 KB: [kgroup][px] = h[px][4kg..4kg+3]
    __shared__ float cn_lds[512];
    __shared__ int   mis_lds[256];
    __shared__ int   rlist[256];
    __shared__ float hex[8][64];        // per-wave exact-h scratch
    __shared__ int   rcnt;
    const int blk = blockIdx.x;
    const int b = blk >> 2, strip = blk & 3;
    const int r0 = strip * 8;
    const int tid = threadIdx.x;
    const size_t base = (size_t)blk * 256;
    if (tid == 0) rcnt = 0;
    cn_lds[tid] = cnorm[tid];
    // ---- phase 1: stage + split h1 tile ----
    for (int i = tid; i < 640; i += 512) {   // zero-pad x columns 0 and 33
        int ci = i & 31, rem = i >> 5;       // rem 0..19
        int ry = rem >> 1, colx = (rem & 1) * 33;
        int idx = (ry * 34 + colx) * CI_P + ci;
        Ah[idx] = (hf)0.f;
        Al[idx] = (hf)0.f;
    }
    #pragma unroll
    for (int r = 0; r < 5; ++r) {        // 2560 float4 = 10 rows x 32x x 8ci4
        int j = tid + r * 512;
        int ci4 = j & 7, xc = (j >> 3) & 31, ry = j >> 8;   // ry 0..9
        int gy = r0 - 1 + ry;
        float4 v = make_float4(0.f, 0.f, 0.f, 0.f);
        if (gy >= 0 && gy < 32)
            v = *(const float4*)(h1 + ((size_t)b * NPX + gy * 32 + xc) * 32 + ci4 * 4);
        int bi = (ry * 34 + xc + 1) * CI_P + ci4 * 4;
        float fv[4] = {v.x, v.y, v.z, v.w};
        #pragma unroll
        for (int q = 0; q < 4; ++q) {
            float a = fv[q] * 256.f;               // exact pow2 scale
            hf h0 = (hf)a;
            float rl = (a - (float)h0) * 2048.f;   // exact
            Ah[bi + q] = h0;
            Al[bi + q] = (hf)rl;
        }
    }
    __syncthreads();
    const int w = tid >> 6, l = tid & 63;   // wave w owns px [w*32, w*32+32)
    const int co16 = l & 15, g = l >> 4;    // conv2: i16/j4 == screener: co/g
    // ---- phase 1b: conv2 MFMA, epilogue -> Ats ----
    #pragma unroll 1
    for (int ntp = 0; ntp < 2; ++ntp) {     // N-tile pairs: co [0,32), [32,64)
        f32x4 hi[2][2], mid[2][2], llt[2][2];   // [m-subtile][ntl]
        #pragma unroll
        for (int s = 0; s < 2; ++s)
            #pragma unroll
            for (int n = 0; n < 2; ++n) {
                hi[s][n] = f32x4{0.f, 0.f, 0.f, 0.f};
                mid[s][n] = f32x4{0.f, 0.f, 0.f, 0.f};
                llt[s][n] = f32x4{0.f, 0.f, 0.f, 0.f};
            }
        #pragma unroll 1
        for (int s9 = 0; s9 < 9; ++s9) {
            const int dy = s9 / 3, dx = s9 - dy * 3;
            hf8 a_h[2], a_l[2];
            #pragma unroll
            for (int s = 0; s < 2; ++s) {
                int ofs = ((w + dy) * 34 + (s * 16 + co16 + dx)) * CI_P + 8 * g;
                a_h[s] = *(const hf8*)(Ah + ofs);
                a_l[s] = *(const hf8*)(Al + ofs);
            }
            #pragma unroll
            for (int ntl = 0; ntl < 2; ++ntl) {
                const int nt = ntp * 2 + ntl;
                const int wofs = (s9 * 64 + nt * 16 + co16) * 32 + 8 * g;
                const hf8 b_h = *(const hf8*)(wTh + wofs);
                const hf8 b_l = *(const hf8*)(wTl + wofs);
                #pragma unroll
                for (int s = 0; s < 2; ++s) {
                    hi[s][ntl]  = mfma16(a_h[s], b_h, hi[s][ntl]);
                    mid[s][ntl] = mfma16(a_h[s], b_l, mid[s][ntl]);
                    mid[s][ntl] = mfma16(a_l[s], b_h, mid[s][ntl]);
                    llt[s][ntl] = mfma16(a_l[s], b_l, llt[s][ntl]);
                }
            }
        }
        #pragma unroll
        for (int ntl = 0; ntl < 2; ++ntl) {
            const int co = (ntp * 2 + ntl) * 16 + co16;
            const float bco = c2b[co];
            #pragma unroll
            for (int s = 0; s < 2; ++s) {
                #pragma unroll
                for (int r = 0; r < 4; ++r) {
                    float comb = fmaf(mid[s][ntl][r], 4.8828125e-4f,
                                 fmaf(llt[s][ntl][r], 2.384185791015625e-7f,
                                      hi[s][ntl][r]));
                    float hv = fmaxf(
                        __fadd_rn(__fmul_rn(comb, 1.52587890625e-5f), bco), 0.f);
                    int pxl = w * 32 + s * 16 + g * 4 + r;
                    ((float*)&Ats[co >> 2][pxl])[co & 3] = hv;
                }
            }
        }
    }
    __syncthreads();
    // ---- phase 2: screener (R12 verbatim; A-frags wave-local from Ats) ----
    const int co = co16;
    const int pxw = w * 32;
    hf8 ah[2][2], al[2][2];
    #pragma unroll
    for (int s = 0; s < 2; ++s)
        #pragma unroll
        for (int ks = 0; ks < 2; ++ks) {
            float4 q0 = Ats[ks * 8 + g * 2 + 0][pxw + s * 16 + co];
            float4 q1 = Ats[ks * 8 + g * 2 + 1][pxw + s * 16 + co];
            float fv[8] = {q0.x, q0.y, q0.z, q0.w, q1.x, q1.y, q1.z, q1.w};
            #pragma unroll
            for (int j = 0; j < 8; ++j) {
                float fa = fv[j] * 256.f;
                hf h0 = (hf)fa;
                float rl = (fa - (float)h0) * 2048.f;
                ah[s][ks][j] = h0;
                al[s][ks][j] = (hf)rl;
            }
        }
    float minv[2][4], min2[2][4];
    int   mini[2][4];
    #pragma unroll
    for (int s = 0; s < 2; ++s)
        #pragma unroll
        for (int r = 0; r < 4; ++r) {
            minv[s][r] = 3.4e38f; min2[s][r] = 3.4e38f; mini[s][r] = 0;
        }
    const hf* pbh = cbh + (size_t)co * 64 + g * 8;
    const hf* pbl = cbl + (size_t)co * 64 + g * 8;
    #pragma unroll 1
    for (int t = 0; t < 32; ++t) {
        const hf8 bh0 = *(const hf8*)(pbh + (size_t)t * 1024);
        const hf8 bh1 = *(const hf8*)(pbh + (size_t)t * 1024 + 32);
        const hf8 bl0 = *(const hf8*)(pbl + (size_t)t * 1024);
        const hf8 bl1 = *(const hf8*)(pbl + (size_t)t * 1024 + 32);
        const float cn = cn_lds[t * 16 + co];
        #pragma unroll
        for (int s = 0; s < 2; ++s) {
            f32x4 hi = {0.f, 0.f, 0.f, 0.f};
            f32x4 lo = {0.f, 0.f, 0.f, 0.f};
            f32x4 ll = {0.f, 0.f, 0.f, 0.f};
            lo = mfma16(ah[s][0], bl0, lo);
            lo = mfma16(al[s][0], bh0, lo);
            ll = mfma16(al[s][0], bl0, ll);
            hi = mfma16(ah[s][0], bh0, hi);
            lo = mfma16(ah[s][1], bl1, lo);
            lo = mfma16(al[s][1], bh1, lo);
            ll = mfma16(al[s][1], bl1, ll);
            hi = mfma16(ah[s][1], bh1, hi);
            #pragma unroll
            for (int r = 0; r < 4; ++r) {
                float comb = fmaf(lo[r], 4.8828125e-4f,
                             fmaf(ll[r], 2.384185791015625e-7f, hi[r]));
                float d = __fsub_rn(cn, __fmul_rn(3.0517578125e-5f, comb));
                if (d < minv[s][r]) {
                    min2[s][r] = minv[s][r];
                    minv[s][r] = d; mini[s][r] = t * 16 + co;
                } else if (d < min2[s][r]) {
                    min2[s][r] = d;
                }
            }
        }
    }
    #pragma unroll
    for (int s = 0; s < 2; ++s)
        #pragma unroll
        for (int r = 0; r < 4; ++r) {
            float v1 = minv[s][r], v2 = min2[s][r];
            int i1 = mini[s][r];
            #pragma unroll
            for (int off = 1; off < 16; off <<= 1) {
                float vo  = __shfl_xor(v1, off, 64);
                int   io  = __shfl_xor(i1, off, 64);
                float v2o = __shfl_xor(v2, off, 64);
                if (vo < v1 || (vo == v1 && io < i1)) {
                    v2 = fminf(v1, v2o);
                    v1 = vo; i1 = io;
                } else {
                    v2 = fminf(v2, vo);
                }
            }
            if (co == 0) {
                int pxo = pxw + s * 16 + g * 4 + r;
                mis_lds[pxo] = i1;
                if (v2 - v1 <= TAU) {
                    int slot = atomicAdd(&rcnt, 1);
                    rlist[slot] = pxo;
                }
            }
        }
    __syncthreads();
    // ---- certified exact rescue: wave-local, barrier-free, rr%8 == wave ----
    const int nresc = rcnt;
    for (int rr = w; rr < nresc; rr += 8) {
        const int px = rlist[rr];
        const int gpx = (int)base + px;
        const int bimg = gpx >> 10, pp = gpx & 1023;
        const int py = pp >> 5, pxx = pp & 31;
        float* hx = &hex[w][0];
        {   // lane l = co: exact conv2 chain (s9 asc, ci asc), coalesced c2w reads
            float acc = 0.f;
            #pragma unroll 1
            for (int s9 = 0; s9 < 9; ++s9) {
                const int dy = s9 / 3, dx = s9 - dy * 3;
                const int gy = py + dy - 1, gx = pxx + dx - 1;
                if (gy >= 0 && gy < 32 && gx >= 0 && gx < 32) {
                    const float* hp = h1 + ((size_t)bimg * NPX + gy * 32 + gx) * 32;
                    const float* wp = c2w + s9 * 2048 + l;
                    #pragma unroll
                    for (int ci = 0; ci < 32; ++ci)
                        acc = fmaf(hp[ci], wp[ci * 64], acc);
                }
            }
            hx[l] = fmaxf(__fadd_rn(acc, c2b[l]), 0.f);
        }
        // same-wave LDS write->read: compiler-inserted lgkmcnt wait, no barrier needed
        const float Hp = np_sumsq64(hx, 1);   // exact H (broadcast reads)
        float bv = 3.4e38f; int bi2 = 0;
        const float* crow = cb + (size_t)(l * 8) * 64;
        #pragma unroll 1
        for (int c = 0; c < 8; ++c) {         // in-lane codes ascending, strict <
            float acc0 = 0.f;
            const float* cr = crow + c * 64;
            #pragma unroll
            for (int kg = 0; kg < 16; ++kg) {
                acc0 = fmaf(hx[kg*4+0], cr[kg*4+0], acc0);
                acc0 = fmaf(hx[kg*4+1], cr[kg*4+1], acc0);
                acc0 = fmaf(hx[kg*4+2], cr[kg*4+2], acc0);
                acc0 = fmaf(hx[kg*4+3], cr[kg*4+3], acc0);
            }
            float d = __fadd_rn(__fsub_rn(Hp, __fmul_rn(2.f, acc0)),
                                cn_lds[l * 8 + c]);
            if (d < bv) { bv = d; bi2 = l * 8 + c; }
        }
        #pragma unroll
        for (int off = 1; off < 64; off <<= 1) {   // lexicographic (v,idx): first occurrence
            float vo = __shfl_xor(bv, off, 64);
            int   io = __shfl_xor(bi2, off, 64);
            if (vo < bv || (vo == bv && io < bi2)) { bv = vo; bi2 = io; }
        }
        if (l == 0) mis_lds[px] = bi2;
    }
    __syncthreads();
    // ---- outputs + loss epilogue ----
    if (tid < 256) {
        int bi = mis_lds[tid];
        idxout[base + tid] = bi;
        fidx[base + tid] = (float)bi;
        float ls = 0.f;
        const float* crow = cb + (size_t)bi * 64;
        #pragma unroll
        for (int kg = 0; kg < 16; ++kg) {
            float4 a = Ats[kg][tid];
            float d0 = crow[kg*4+0] - a.x;
            float d1 = crow[kg*4+1] - a.y;
            float d2 = crow[kg*4+2] - a.z;
            float d3 = crow[kg*4+3] - a.w;
            ls = fmaf(d0, d0, ls); ls = fmaf(d1, d1, ls);
            ls = fmaf(d2, d2, ls); ls = fmaf(d3, d3, ls);
        }
        #pragma unroll
        for (int off = 32; off > 0; off >>= 1)
            ls += __shfl_down(ls, off, 64);
        if ((tid & 63) == 0) atomicAdd(lossacc, ls);
    }
}

// ---------------- fc1 via 3-term split-f16 MFMA: emb @ w1 -> K-split partials ----------------
__global__ __launch_bounds__(256) void k_fc1(const int* __restrict__ idxw,
                                             const hf* __restrict__ cbh,
                                             const hf* __restrict__ cbl,
                                             const hf* __restrict__ w1h,
                                             const hf* __restrict__ w1l,
                                             float* __restrict__ part) {
    const int kchunk = blockIdx.x;       // 0..63  (16 pixels = K 1024)
    const int mtile  = blockIdx.y;       // 0..7   (64 images)
    const int tid = threadIdx.x;
    const int w = tid >> 6, l = tid & 63;    // wave = 16-img subtile
    const int co = l & 15, g = l >> 4;
    const int mbase = mtile * 64 + w * 16;
    f32x4 hi[8], mid[8];
    #pragma unroll
    for (int n = 0; n < 8; ++n) {
        hi[n] = f32x4{0.f, 0.f, 0.f, 0.f};
        mid[n] = f32x4{0.f, 0.f, 0.f, 0.f};
    }
    int code = 0;
    #pragma unroll 1
    for (int kstep = 0; kstep < 32; ++kstep) {   // 32 x K=32
        if ((kstep & 1) == 0) {
            const int pix = kchunk * 16 + (kstep >> 1);
            code = idxw[(size_t)(mbase + co) * NPX + pix];
        }
        const int koff = (kstep & 1) * 32 + g * 8;
        const hf8 ah = *(const hf8*)(cbh + ((size_t)code << 6) + koff);
        const hf8 al = *(const hf8*)(cbl + ((size_t)code << 6) + koff);
        const size_t k8b = (size_t)(kchunk * 128 + kstep * 4 + g) * 1024;
        #pragma unroll
        for (int n = 0; n < 8; ++n) {
            const hf8 bh = *(const hf8*)(w1h + k8b + (n * 16 + co) * 8);
            const hf8 bl = *(const hf8*)(w1l + k8b + (n * 16 + co) * 8);
            hi[n]  = mfma16(ah, bh, hi[n]);
            mid[n] = mfma16(ah, bl, mid[n]);
            mid[n] = mfma16(al, bh, mid[n]);
        }
    }
    #pragma unroll
    for (int n = 0; n < 8; ++n)
        #pragma unroll
        for (int r = 0; r < 4; ++r) {
            float comb = fmaf(mid[n][r], 4.8828125e-4f, hi[n][r]);
            const int img = mtile * 64 + w * 16 + g * 4 + r;
            part[((size_t)kchunk * 512 + img) * 128 + n * 16 + co] =
                __fmul_rn(comb, 1.52587890625e-5f);
        }
}

// ---------------- reduce partials + b1 + relu -> x0 [512,128] ----------------
__global__ __launch_bounds__(256) void k_reduce(const float* __restrict__ part,
                                                const float* __restrict__ b1,
                                                float* __restrict__ x0) {
    int t = blockIdx.x * 256 + threadIdx.x;  // 0..65535
    float s = b1[t & 127];
    for (int ch = 0; ch < 64; ++ch)
        s += part[(size_t)ch * 65536 + t];
    x0[t] = fmaxf(s, 0.f);
}

// ---------------- fused trunk + heads (+ folded vq-loss finalize) ----------------
__device__ __forceinline__ void mlp_layer(const float in[][16], float out[][16],
                                          const float* __restrict__ W,
                                          const float* __restrict__ bias,
                                          int tid, bool dorelu) {
    const int lane = tid & 63, wv = tid >> 6;
    const int img = lane & 15, cg = lane >> 4;
    const int c0 = wv * 32 + cg * 8;
    float acc[8] = {0,0,0,0,0,0,0,0};
    for (int k = 0; k < 128; ++k) {
        float a = in[k][img];
        float4 wA = *(const float4*)(W + (size_t)k * 128 + c0);
        float4 wB = *(const float4*)(W + (size_t)k * 128 + c0 + 4);
        acc[0] = fmaf(a, wA.x, acc[0]);
        acc[1] = fmaf(a, wA.y, acc[1]);
        acc[2] = fmaf(a, wA.z, acc[2]);
        acc[3] = fmaf(a, wA.w, acc[3]);
        acc[4] = fmaf(a, wB.x, acc[4]);
        acc[5] = fmaf(a, wB.y, acc[5]);
        acc[6] = fmaf(a, wB.z, acc[6]);
        acc[7] = fmaf(a, wB.w, acc[7]);
    }
    #pragma unroll
    for (int c = 0; c < 8; ++c) {
        float v = acc[c] + bias[c0 + c];
        if (dorelu) v = fmaxf(v, 0.f);
        out[c0 + c][img] = v;
    }
}

__global__ __launch_bounds__(256) void k_trunk(const float* __restrict__ x0,
        const float* __restrict__ w2, const float* __restrict__ b2,
        const float* __restrict__ w3, const float* __restrict__ b3,
        const float* __restrict__ wa1, const float* __restrict__ ba1,
        const float* __restrict__ wa2, const float* __restrict__ ba2,
        const float* __restrict__ wc1, const float* __restrict__ bc1,
        const float* __restrict__ wc2, const float* __restrict__ bc2,
        const float* __restrict__ wc3, const float* __restrict__ bc3,
        float* __restrict__ probs, float* __restrict__ value,
        const float* __restrict__ accv, float* __restrict__ vqloss) {
    __shared__ float bufA[128][16], bufB[128][16], bufC[128][16];
    __shared__ float lg[16][10];
    const int tid = threadIdx.x;
    const int m0 = blockIdx.x * 16;
    if (blockIdx.x == 0 && tid == 0)     // folded k_vqfinal (k_cvq complete: stream order)
        vqloss[0] = accv[0] * 1.25f / 33554432.f;
    for (int r = 0; r < 2; ++r) {
        int j = tid + r * 256;                 // 0..511
        int img = j >> 5, k4 = j & 31;
        float4 v = *(const float4*)(x0 + (size_t)(m0 + img) * 128 + k4 * 4);
        bufA[k4*4+0][img] = v.x;
        bufA[k4*4+1][img] = v.y;
        bufA[k4*4+2][img] = v.z;
        bufA[k4*4+3][img] = v.w;
    }
    __syncthreads();
    mlp_layer(bufA, bufB, w2, b2, tid, true);   __syncthreads();
    mlp_layer(bufB, bufC, w3, b3, tid, true);   __syncthreads();  // C = e3
    mlp_layer(bufC, bufA, wa1, ba1, tid, true); __syncthreads();  // A = a1
    if (tid < 160) {
        int img = tid & 15, col = tid >> 4;     // col 0..9
        float s = 0.f;
        for (int k = 0; k < 128; ++k)
            s = fmaf(bufA[k][img], wa2[(size_t)k * 10 + col], s);
        lg[img][col] = s + ba2[col];
    }
    __syncthreads();
    if (tid < 16) {
        int img = tid;
        float m = lg[img][0];
        #pragma unroll
        for (int c = 1; c < 10; ++c) m = fmaxf(m, lg[img][c]);
        float e[10]; float s = 0.f;
        #pragma unroll
        for (int c = 0; c < 10; ++c) { e[c] = expf(lg[img][c] - m); s += e[c]; }
        float inv = 1.f / s;
        #pragma unroll
        for (int c = 0; c < 10; ++c)
            probs[(size_t)(m0 + img) * 10 + c] = e[c] * inv;
    }
    __syncthreads();
    mlp_layer(bufC, bufB, wc1, bc1, tid, true); __syncthreads();
    mlp_layer(bufB, bufA, wc2, bc2, tid, true); __syncthreads();  // A = c2
    if (tid < 16) {
        int img = tid;
        float s = 0.f;
        for (int k = 0; k < 128; ++k)
            s = fmaf(bufA[k][img], wc3[k], s);
        value[m0 + img] = s + bc3[0];
    }
}

extern "C" void kernel_launch(void* const* d_in, const int* in_sizes, int n_in,
                              void* d_out, int out_size, void* d_ws, size_t ws_size,
                              hipStream_t stream) {
    const float* x   = (const float*)d_in[0];
    const float* c1w = (const float*)d_in[1];
    const float* c1b = (const float*)d_in[2];
    const float* c2w = (const float*)d_in[3];
    const float* c2b = (const float*)d_in[4];
    const float* cb  = (const float*)d_in[5];
    const float* w1  = (const float*)d_in[6];
    const float* b1  = (const float*)d_in[7];
    const float* w2  = (const float*)d_in[8];
    const float* b2  = (const float*)d_in[9];
    const float* w3  = (const float*)d_in[10];
    const float* b3  = (const float*)d_in[11];
    const float* wa1 = (const float*)d_in[12];
    const float* ba1 = (const float*)d_in[13];
    const float* wa2 = (const float*)d_in[14];
    const float* ba2 = (const float*)d_in[15];
    const float* wc1 = (const float*)d_in[16];
    const float* bc1 = (const float*)d_in[17];
    const float* wc2 = (const float*)d_in[18];
    const float* bc2 = (const float*)d_in[19];
    const float* wc3 = (const float*)d_in[20];
    const float* bc3 = (const float*)d_in[21];

    float* out = (float*)d_out;
    float* ws  = (float*)d_ws;

    // workspace layout (floats):
    float* h1    = ws;                                   // [0, 16777216)  live until k_cvq done
    float* part  = ws;                                   // [0, 4194304)   post-k_cvq (fc1)
    float* x0    = ws + (size_t)4 * 1024 * 1024;         // 65,536 (post-k_cvq)
    hf*    w1Th  = (hf*)(ws + (size_t)16777216);         // 8,388,608 hf (free region: no h)
    hf*    w1Tl  = (hf*)(ws + (size_t)20971520);         // 8,388,608 hf
    int*   idxw  = (int*)(ws + (size_t)50331648);        // 524,288 ints
    float* cn    = ws + (size_t)50855936;                //     512
    float* accv  = ws + (size_t)50856448;                //       1
    hf*    cbh   = (hf*)(ws + (size_t)50857984);         //  32,768 f16
    hf*    cbl   = (hf*)(ws + (size_t)50874368);         //  32,768 f16
    hf*    wTh   = (hf*)(ws + (size_t)50890752);         //  18,432 f16
    hf*    wTl   = (hf*)(ws + (size_t)50899968);         //  18,432 f16

    hipLaunchKernelGGL(k_conv1,  dim3(512),   dim3(256), 0, stream, x, c1w, c1b, h1,
                       cb, c2w, w1, cn, cbh, cbl, wTh, wTl, w1Th, w1Tl, accv);
    hipLaunchKernelGGL(k_cvq,    dim3(2048),  dim3(512), 0, stream, h1, wTh, wTl,
                       c2w, c2b, cb, cbh, cbl, cn, idxw, out + 5633, accv);
    hipLaunchKernelGGL(k_fc1,    dim3(64, 8), dim3(256), 0, stream, idxw, cbh, cbl,
                       w1Th, w1Tl, part);
    hipLaunchKernelGGL(k_reduce, dim3(256),   dim3(256), 0, stream, part, b1, x0);
    hipLaunchKernelGGL(k_trunk,  dim3(32),    dim3(256), 0, stream, x0,
                       w2, b2, w3, b3, wa1, ba1, wa2, ba2,
                       wc1, bc1, wc2, bc2, wc3, bc3,
                       out, out + 5120, accv, out + 5632);
}